// Round 4
// baseline (61.189 us; speedup 1.0000x reference)
//
#include <hip/hip_runtime.h>
#include <math.h>

#define VOXEL 32
#define NCELL (VOXEL * VOXEL)   // 1024 cells per batch
#define CHUNK 16                // features per block: 16 f32 = 64 B = one cacheline
#define BLOCK_T 1024            // threads per block (== NCELL)

// Order-preserving f32 <-> u32 encoding: unsigned compare == float compare.
// enc(any real float, incl -inf) >= 0x007FFFFF > 0, so 0 marks "untouched".
__device__ __forceinline__ unsigned int enc_f32(float f) {
    unsigned int u = __float_as_uint(f);
    return (u & 0x80000000u) ? ~u : (u | 0x80000000u);
}
__device__ __forceinline__ float dec_f32(unsigned int u) {
    if (u == 0u) return 0.0f;  // untouched cell
    return __uint_as_float((u & 0x80000000u) ? (u ^ 0x80000000u) : ~u);
}

__device__ __forceinline__ int local_cell(float x, float y) {
    int gx = (int)(x * (float)(VOXEL - 1));  // trunc toward zero == astype(int32)
    int gy = (int)(y * (float)(VOXEL - 1));
    gx = min(max(gx, 0), VOXEL - 1);
    gy = min(max(gy, 0), VOXEL - 1);
    return gy * VOXEL + gx;
}

// One block per (batch, feature-chunk). Streams the batch's points linearly,
// scatter-maxes into a 64 KB LDS accumulator, then writes its exclusive
// output slab. acc layout is transposed [CHUNK][NCELL] so a wave's fixed-k
// atomics spread across banks by cell%32 (random -> ~2-way, free per m136).
__global__ void __launch_bounds__(BLOCK_T)
voxelize_fused(const float* __restrict__ feat,
               const float* __restrict__ coords,
               float* __restrict__ out,
               int N, int F) {
    __shared__ unsigned int acc[CHUNK * NCELL];  // 64 KB

    const int b     = blockIdx.x / (F / CHUNK);
    const int chunk = blockIdx.x % (F / CHUNK);
    const int t     = threadIdx.x;

#pragma unroll
    for (int k = 0; k < CHUNK; ++k) acc[k * NCELL + t] = 0u;
    __syncthreads();

    const float* cb = coords + (size_t)b * N * 2;
    const float* fb = feat + (size_t)b * N * F + chunk * CHUNK;

    for (int p = t; p < N; p += BLOCK_T) {
        const float x = cb[p * 2 + 0];
        const float y = cb[p * 2 + 1];
        const int cell = local_cell(x, y);

        const float4* src = (const float4*)(fb + (size_t)p * F);
        const float4 v0 = src[0];
        const float4 v1 = src[1];
        const float4 v2 = src[2];
        const float4 v3 = src[3];

        atomicMax(&acc[0  * NCELL + cell], enc_f32(v0.x));
        atomicMax(&acc[1  * NCELL + cell], enc_f32(v0.y));
        atomicMax(&acc[2  * NCELL + cell], enc_f32(v0.z));
        atomicMax(&acc[3  * NCELL + cell], enc_f32(v0.w));
        atomicMax(&acc[4  * NCELL + cell], enc_f32(v1.x));
        atomicMax(&acc[5  * NCELL + cell], enc_f32(v1.y));
        atomicMax(&acc[6  * NCELL + cell], enc_f32(v1.z));
        atomicMax(&acc[7  * NCELL + cell], enc_f32(v1.w));
        atomicMax(&acc[8  * NCELL + cell], enc_f32(v2.x));
        atomicMax(&acc[9  * NCELL + cell], enc_f32(v2.y));
        atomicMax(&acc[10 * NCELL + cell], enc_f32(v2.z));
        atomicMax(&acc[11 * NCELL + cell], enc_f32(v2.w));
        atomicMax(&acc[12 * NCELL + cell], enc_f32(v3.x));
        atomicMax(&acc[13 * NCELL + cell], enc_f32(v3.y));
        atomicMax(&acc[14 * NCELL + cell], enc_f32(v3.z));
        atomicMax(&acc[15 * NCELL + cell], enc_f32(v3.w));
    }
    __syncthreads();

    // Thread t owns cell t: decode 16 values, write 64 B contiguous.
    float r[CHUNK];
#pragma unroll
    for (int k = 0; k < CHUNK; ++k) r[k] = dec_f32(acc[k * NCELL + t]);

    float* dst = out + ((size_t)b * NCELL + t) * F + chunk * CHUNK;
    float4* d4 = (float4*)dst;
#pragma unroll
    for (int k = 0; k < CHUNK / 4; ++k)
        d4[k] = make_float4(r[4 * k + 0], r[4 * k + 1], r[4 * k + 2], r[4 * k + 3]);
}

// ---------- fallback path (round-1 atomic version, any shape) ----------

__global__ void voxel_scatter_max(const float* __restrict__ feat,
                                  const float* __restrict__ coords,
                                  unsigned int* __restrict__ out,
                                  int BN, int N, int F) {
    int gid   = blockIdx.x * blockDim.x + threadIdx.x;
    int point = gid / (F / 4);
    int fi    = gid % (F / 4);
    if (point >= BN) return;
    int b = point / N;
    int idx = b * NCELL + local_cell(coords[(size_t)point * 2], coords[(size_t)point * 2 + 1]);
    const float4 v = *(const float4*)(feat + (size_t)point * F + fi * 4);
    unsigned int* o = out + (size_t)idx * F + fi * 4;
    atomicMax(o + 0, enc_f32(v.x));
    atomicMax(o + 1, enc_f32(v.y));
    atomicMax(o + 2, enc_f32(v.z));
    atomicMax(o + 3, enc_f32(v.w));
}

__global__ void voxel_decode(unsigned int* __restrict__ out, int n4) {
    int i = blockIdx.x * blockDim.x + threadIdx.x;
    if (i >= n4) return;
    uint4 u = ((const uint4*)out)[i];
    float4 f;
    f.x = dec_f32(u.x);
    f.y = dec_f32(u.y);
    f.z = dec_f32(u.z);
    f.w = dec_f32(u.w);
    ((float4*)out)[i] = f;
}

// ---------- launch ----------

extern "C" void kernel_launch(void* const* d_in, const int* in_sizes, int n_in,
                              void* d_out, int out_size, void* d_ws, size_t ws_size,
                              hipStream_t stream) {
    const float* feat   = (const float*)d_in[0];
    const float* coords = (const float*)d_in[1];

    const int BN = in_sizes[1] / 2;                 // 131072 points
    const int F  = in_sizes[0] / BN;                // 256
    const int B  = out_size / (NCELL * F);          // 16
    const int N  = BN / B;                          // 8192

    const bool fast_ok = (F % CHUNK == 0) && (F % 4 == 0) && (B * N == BN) &&
                         (B * NCELL * F == out_size);

    if (fast_ok) {
        const int nblocks = B * (F / CHUNK);  // 256
        voxelize_fused<<<nblocks, BLOCK_T, 0, stream>>>(feat, coords, (float*)d_out, N, F);
    } else {
        unsigned int* out = (unsigned int*)d_out;
        hipMemsetAsync(d_out, 0, (size_t)out_size * sizeof(float), stream);
        int threads = BN * (F / 4);
        voxel_scatter_max<<<(threads + 255) / 256, 256, 0, stream>>>(feat, coords, out, BN, N, F);
        int n4 = out_size / 4;
        voxel_decode<<<(n4 + 255) / 256, 256, 0, stream>>>(out, n4);
    }
}